// Round 1
// baseline (56.216 us; speedup 1.0000x reference)
//
#include <hip/hip_runtime.h>

#define N_P 256
#define N_T 32
#define OFFDIAG 65280   // 256*255
#define QROWS 1024      // 32*32

// ---------------------------------------------------------------------------
// Kernel 1: iou[32][256] in exact reference fp order + per-proposal best
// (max over 32 targets, first-occurrence argmax).
// ---------------------------------------------------------------------------
__global__ void iou_best_kernel(const float* __restrict__ pb,
                                const float* __restrict__ tb,
                                float* __restrict__ iou,
                                float* __restrict__ bv,
                                int* __restrict__ bidx) {
    __shared__ float t0[N_T], t1[N_T], t2[N_T], t3[N_T], ta[N_T];
    int tid = threadIdx.x;
    if (tid < N_T) {
        float a0 = tb[tid * 4 + 0], a1 = tb[tid * 4 + 1];
        float a2 = tb[tid * 4 + 2], a3 = tb[tid * 4 + 3];
        t0[tid] = a0; t1[tid] = a1; t2[tid] = a2; t3[tid] = a3;
        ta[tid] = ((a2 - a0) + 1.0f) * ((a3 - a1) + 1.0f);   // area_a, ref order
    }
    __syncthreads();
    int p = tid;
    float b0 = pb[p * 4 + 0], b1 = pb[p * 4 + 1];
    float b2 = pb[p * 4 + 2], b3 = pb[p * 4 + 3];
    float areaB = ((b2 - b0) + 1.0f) * ((b3 - b1) + 1.0f);
    float bestv = -1.0f;
    int besti = 0;
    #pragma unroll
    for (int t = 0; t < N_T; ++t) {
        float lt0 = fmaxf(t0[t], b0), lt1 = fmaxf(t1[t], b1);
        float rb0 = fminf(t2[t], b2), rb1 = fminf(t3[t], b3);
        float w = fmaxf((rb0 - lt0) + 1.0f, 0.0f);
        float h = fmaxf((rb1 - lt1) + 1.0f, 0.0f);
        float inter = w * h;
        float v = inter / ((ta[t] + areaB) - inter);  // (area_a+area_b)-inter, ref order
        iou[t * N_P + p] = v;
        if (v > bestv) { bestv = v; besti = t; }      // strict > == first occurrence
    }
    bv[p] = bestv;
    bidx[p] = besti;
}

// ---------------------------------------------------------------------------
// Kernel 2: quality [1024 x 65280] f32. blockIdx.y = pq (GT pair), each block
// stages iou rows p and q (2 KB) in LDS; float4 stores, fully coalesced.
// k -> (i,j): i = k/255, r = k%255, j = r + (r>=i).
// ---------------------------------------------------------------------------
__global__ void quality_kernel(const float* __restrict__ iou,
                               float* __restrict__ qout) {
    int pq = blockIdx.y;
    int p = pq >> 5, q = pq & 31;
    __shared__ float rp[N_P], rq[N_P];
    int tid = threadIdx.x;
    rp[tid] = iou[p * N_P + tid];
    rq[tid] = iou[q * N_P + tid];
    __syncthreads();
    int base = blockIdx.x * 1024 + tid * 4;
    if (base < OFFDIAG) {
        float4 v;
        float* vv = reinterpret_cast<float*>(&v);
        #pragma unroll
        for (int e = 0; e < 4; ++e) {
            int k = base + e;
            int i = (unsigned)k / 255u;
            int r = k - i * 255;
            int j = r + (r >= i ? 1 : 0);
            vv[e] = 0.5f * (rp[i] + rq[j]);
        }
        *reinterpret_cast<float4*>(qout + (size_t)pq * OFFDIAG + base) = v;
    }
}

// ---------------------------------------------------------------------------
// Kernel 3: matched_idxs, labels, proposal box/idx pairs, target box pairs.
// Decomposed matcher: mv = 0.5*(bv[i]+bv[j]); matches = bidx[i]*32+bidx[j].
// ---------------------------------------------------------------------------
__global__ void tail_kernel(const float* __restrict__ pb,
                            const float* __restrict__ tb,
                            const int* __restrict__ tpl,
                            const float* __restrict__ bv,
                            const int* __restrict__ bidx,
                            float* __restrict__ out) {
    int k = blockIdx.x * 256 + threadIdx.x;           // [0, 65280)
    float* matched = out + (size_t)QROWS * OFFDIAG;   // +66,846,720
    float* labels  = matched + OFFDIAG;
    float* pbp     = labels + OFFDIAG;
    float* pip     = pbp + (size_t)OFFDIAG * 8;
    float* tbp     = pip + (size_t)OFFDIAG * 2;

    int i = (unsigned)k / 255u;
    int r = k - i * 255;
    int j = r + (r >= i ? 1 : 0);

    float mv = 0.5f * (bv[i] + bv[j]);
    int mi, lab;
    if (mv < 0.3f)      { mi = -1; lab = 0; }
    else if (mv < 0.5f) { mi = -2; lab = -1; }
    else                { mi = bidx[i] * N_T + bidx[j]; lab = tpl[mi]; }

    matched[k] = (float)mi;
    labels[k]  = (float)lab;

    float4 bi = reinterpret_cast<const float4*>(pb)[i];
    float4 bj = reinterpret_cast<const float4*>(pb)[j];
    reinterpret_cast<float4*>(pbp)[k * 2 + 0] = bi;
    reinterpret_cast<float4*>(pbp)[k * 2 + 1] = bj;
    pip[k * 2 + 0] = (float)i;
    pip[k * 2 + 1] = (float)j;

    if (k < QROWS) {
        int p = k >> 5, q = k & 31;
        reinterpret_cast<float4*>(tbp)[k * 2 + 0] =
            reinterpret_cast<const float4*>(tb)[p];
        reinterpret_cast<float4*>(tbp)[k * 2 + 1] =
            reinterpret_cast<const float4*>(tb)[q];
    }
}

extern "C" void kernel_launch(void* const* d_in, const int* in_sizes, int n_in,
                              void* d_out, int out_size, void* d_ws, size_t ws_size,
                              hipStream_t stream) {
    const float* pb  = (const float*)d_in[0];   // proposal_boxes [256,4]
    const float* tb  = (const float*)d_in[1];   // target_boxes   [32,4]
    const int*   tpl = (const int*)d_in[2];     // target_pair_labels [1024]
    float* out = (float*)d_out;

    float* iou  = (float*)d_ws;                 // 32*256 f32 = 32 KB
    float* bv   = iou + N_T * N_P;              // 256 f32
    int*   bidx = (int*)(bv + N_P);             // 256 i32

    iou_best_kernel<<<1, 256, 0, stream>>>(pb, tb, iou, bv, bidx);
    quality_kernel<<<dim3(64, QROWS), 256, 0, stream>>>(iou, out);
    tail_kernel<<<OFFDIAG / 256, 256, 0, stream>>>(pb, tb, tpl, bv, bidx, out);
}